// Round 6
// baseline (289.328 us; speedup 1.0000x reference)
//
#include <hip/hip_runtime.h>
#include <stdint.h>

#define RT    2336          // routes
#define NTH   512
#define NSL   19            // register slices/thread; slice 18 only for tid<128
#define NBLK  2048          // one block per (b,k): b = blk>>1, k = blk&1
#define BATCH 1024
#define SH1   32.0f         // fixed softmax exponent shift, pass 2 (exact: ratio cancels)
#define SH2   64.0f         // fixed softmax exponent shift, pass 3

// Quad-layout block merge. Each lane holds (l, a[4]) for o-quad qo = tid&3.
// Per-class totals land in wave-0 lanes 0..3; class q's L is its own full
// denominator (each route contributes to each qo-class exactly once).
__device__ __forceinline__ void merge_quad(float4 a, float l, int tid,
                                           float (*red)[4][5], float* vbuf,
                                           bool last, float* out_cls){
  #pragma unroll
  for (int off = 32; off >= 4; off >>= 1){
    a.x += __shfl_down(a.x, off); a.y += __shfl_down(a.y, off);
    a.z += __shfl_down(a.z, off); a.w += __shfl_down(a.w, off);
    l   += __shfl_down(l,   off);
  }
  const int lane = tid & 63, wid = tid >> 6;
  if (lane < 4){
    red[wid][lane][0] = l;
    red[wid][lane][1] = a.x; red[wid][lane][2] = a.y;
    red[wid][lane][3] = a.z; red[wid][lane][4] = a.w;
  }
  __syncthreads();
  if (tid < 32){                       // wave 0: parallel cross-wave reduce
    int w = tid >> 2, q = tid & 3;
    float L  = red[w][q][0];
    float s0 = red[w][q][1], s1 = red[w][q][2];
    float s2 = red[w][q][3], s3 = red[w][q][4];
    #pragma unroll
    for (int off = 16; off >= 4; off >>= 1){
      L  += __shfl_down(L,  off);
      s0 += __shfl_down(s0, off); s1 += __shfl_down(s1, off);
      s2 += __shfl_down(s2, off); s3 += __shfl_down(s3, off);
    }
    // lanes 0..3: totals for class q = tid
    float inv = 1.f / L;
    s0 *= inv; s1 *= inv; s2 *= inv; s3 *= inv;
    float nq = s0*s0 + s1*s1 + s2*s2 + s3*s3;
    nq += __shfl_xor(nq, 1); nq += __shfl_xor(nq, 2);   // full ||s||^2 on lanes 0..3
    if (tid < 4){
      if (last){
        if (tid == 0) *out_cls = nq / (1.f + nq);       // ||squash(s)|| = n/(1+n)
      } else {
        float f = sqrtf(nq) / (1.f + nq);               // squash scale
        vbuf[4*tid+0] = s0*f; vbuf[4*tid+1] = s1*f;
        vbuf[4*tid+2] = s2*f; vbuf[4*tid+3] = s3*f;
      }
    }
  }
  __syncthreads();
}

// (512,2): 256-VGPR budget so uj[19] (76 VGPRs) stays register-resident.
// (512,4) made the compiler spill uj to scratch: +160 MB HBM traffic (R5).
__global__ void __launch_bounds__(NTH, 2)
caps_route(const float* __restrict__ U, const float* __restrict__ W,
           float* __restrict__ Out){
  __shared__ float red[8][4][5];
  __shared__ float vbuf[16];

  const int tid = threadIdx.x;
  const int qo  = tid & 3;            // my o-quad: o = 4*qo .. 4*qo+3
  const int rg  = tid >> 2;           // route group 0..127
  const int k   = blockIdx.x & 1;
  const int b   = blockIdx.x >> 1;

  const float* Ub = U + (size_t)b * (RT * 4);
  const float* Wk = W + (size_t)k * ((size_t)RT * 64) + qo * 4;

  float4 uj[NSL];                     // fp32 u_ji quads, register-resident
  float4 acc = make_float4(0.f,0.f,0.f,0.f);

  // ---------------- Phase A: build u_ji; fused pass 1 (uniform weights) ----
  // W loads: lane stride 16 B inside 64-B lines, 16 fully-consumed lines per
  // instruction -> fully coalesced. unroll 4 bounds live-load pressure.
  #pragma unroll 4
  for (int s = 0; s < NSL; ++s){
    if (s < NSL-1 || tid < 128){      // wave-uniform guard (slice 18: waves 0-1)
      int route = s*128 + rg;
      float4 u4 = *(const float4*)(Ub + (size_t)route * 4);
      const float* wr = Wk + (size_t)route * 64;
      float4 w0 = *(const float4*)(wr);
      float4 w1 = *(const float4*)(wr + 16);
      float4 w2 = *(const float4*)(wr + 32);
      float4 w3 = *(const float4*)(wr + 48);
      float4 p;
      p.x = u4.x * w0.x; p.y = u4.x * w0.y; p.z = u4.x * w0.z; p.w = u4.x * w0.w;
      p.x = fmaf(u4.y, w1.x, p.x); p.y = fmaf(u4.y, w1.y, p.y);
      p.z = fmaf(u4.y, w1.z, p.z); p.w = fmaf(u4.y, w1.w, p.w);
      p.x = fmaf(u4.z, w2.x, p.x); p.y = fmaf(u4.z, w2.y, p.y);
      p.z = fmaf(u4.z, w2.z, p.z); p.w = fmaf(u4.z, w2.w, p.w);
      p.x = fmaf(u4.w, w3.x, p.x); p.y = fmaf(u4.w, w3.y, p.y);
      p.z = fmaf(u4.w, w3.z, p.z); p.w = fmaf(u4.w, w3.w, p.w);
      uj[s] = p;
      acc.x += p.x; acc.y += p.y; acc.z += p.z; acc.w += p.w;
    } else {
      uj[s] = make_float4(0.f,0.f,0.f,0.f);
    }
  }
  float lcnt = (tid < 128) ? (float)NSL : (float)(NSL-1);  // routes this lane built
  merge_quad(acc, lcnt, tid, red, vbuf, false, nullptr);   // v0 = squash(s0)
  float4 v0 = make_float4(vbuf[4*qo], vbuf[4*qo+1], vbuf[4*qo+2], vbuf[4*qo+3]);

  // ---------------- Pass 2: d = uji.v0 ; c = softmax(d); s1 ---------------
  acc = make_float4(0.f,0.f,0.f,0.f); float l = 0.f;
  #pragma unroll
  for (int s = 0; s < NSL; ++s){
    float4 p = uj[s];
    float d = fmaf(p.x, v0.x, fmaf(p.y, v0.y, fmaf(p.z, v0.z, p.w * v0.w)));
    d += __shfl_xor(d, 1); d += __shfl_xor(d, 2);          // full route dot
    if (s < NSL-1 || tid < 128){
      float e = __expf(d - SH1);
      l += e;
      acc.x = fmaf(e, p.x, acc.x); acc.y = fmaf(e, p.y, acc.y);
      acc.z = fmaf(e, p.z, acc.z); acc.w = fmaf(e, p.w, acc.w);
    }
  }
  merge_quad(acc, l, tid, red, vbuf, false, nullptr);      // v1 = squash(s1)
  // b2 = uji.v0 + uji.v1 = uji.(v0+v1): pass 3 dots with vsum, no d1 storage
  float4 vs = make_float4(v0.x + vbuf[4*qo],   v0.y + vbuf[4*qo+1],
                          v0.z + vbuf[4*qo+2], v0.w + vbuf[4*qo+3]);

  // ---------------- Pass 3: b2 = uji.(v0+v1) ; c = softmax; s2 ------------
  acc = make_float4(0.f,0.f,0.f,0.f); l = 0.f;
  #pragma unroll
  for (int s = 0; s < NSL; ++s){
    float4 p = uj[s];
    float d = fmaf(p.x, vs.x, fmaf(p.y, vs.y, fmaf(p.z, vs.z, p.w * vs.w)));
    d += __shfl_xor(d, 1); d += __shfl_xor(d, 2);
    if (s < NSL-1 || tid < 128){
      float e = __expf(d - SH2);
      l += e;
      acc.x = fmaf(e, p.x, acc.x); acc.y = fmaf(e, p.y, acc.y);
      acc.z = fmaf(e, p.z, acc.z); acc.w = fmaf(e, p.w, acc.w);
    }
  }
  merge_quad(acc, l, tid, red, vbuf, true, Out + blockIdx.x); // logit -> Out[b*2+k]
}

// In-place 2-way softmax over k: Out[b,0..1] fp32
__global__ void caps_softmax(float* __restrict__ Out){
  int b = blockIdx.x * blockDim.x + threadIdx.x;
  if (b < BATCH){
    float2* p = (float2*)Out;
    float2 c = p[b];
    float m  = fmaxf(c.x, c.y);
    float e0 = __expf(c.x - m), e1 = __expf(c.y - m);
    float inv = 1.f / (e0 + e1);
    p[b] = make_float2(e0 * inv, e1 * inv);
  }
}

extern "C" void kernel_launch(void* const* d_in, const int* in_sizes, int n_in,
                              void* d_out, int out_size, void* d_ws, size_t ws_size,
                              hipStream_t stream) {
  const float* U = (const float*)d_in[0];   // [1024, 2336, 4] fp32
  const float* W = (const float*)d_in[1];   // [2, 2336, 4, 16] fp32
  float* Out = (float*)d_out;               // [1024, 2] fp32
  caps_route<<<dim3(NBLK), dim3(NTH), 0, stream>>>(U, W, Out);
  caps_softmax<<<dim3(BATCH / 256), dim3(256), 0, stream>>>(Out);
}

// Round 7
// 167.017 us; speedup vs baseline: 1.7323x; 1.7323x over previous
//
#include <hip/hip_runtime.h>
#include <stdint.h>

#define RT    2336          // routes
#define NTH   512
#define NSL   19            // register slices/thread; slice 18 only for tid<128
#define NBLK  2048          // one block per (b,k): b = blk>>1, k = blk&1
#define BATCH 1024
#define SH1   32.0f         // fixed softmax exponent shift, pass 2 (exact: ratio cancels)
#define SH2   64.0f         // fixed softmax exponent shift, pass 3

// Quad-layout block merge. Each lane holds (l, a[4]) for o-quad qo = tid&3.
// Per-class totals land in wave-0 lanes 0..3; class q's L is its own full
// denominator (each route contributes to each qo-class exactly once).
__device__ __forceinline__ void merge_quad(float4 a, float l, int tid,
                                           float (*red)[4][5], float* vbuf,
                                           bool last, float* out_cls){
  #pragma unroll
  for (int off = 32; off >= 4; off >>= 1){
    a.x += __shfl_down(a.x, off); a.y += __shfl_down(a.y, off);
    a.z += __shfl_down(a.z, off); a.w += __shfl_down(a.w, off);
    l   += __shfl_down(l,   off);
  }
  const int lane = tid & 63, wid = tid >> 6;
  if (lane < 4){
    red[wid][lane][0] = l;
    red[wid][lane][1] = a.x; red[wid][lane][2] = a.y;
    red[wid][lane][3] = a.z; red[wid][lane][4] = a.w;
  }
  __syncthreads();
  if (tid < 32){                       // wave 0: parallel cross-wave reduce
    int w = tid >> 2, q = tid & 3;
    float L  = red[w][q][0];
    float s0 = red[w][q][1], s1 = red[w][q][2];
    float s2 = red[w][q][3], s3 = red[w][q][4];
    #pragma unroll
    for (int off = 16; off >= 4; off >>= 1){
      L  += __shfl_down(L,  off);
      s0 += __shfl_down(s0, off); s1 += __shfl_down(s1, off);
      s2 += __shfl_down(s2, off); s3 += __shfl_down(s3, off);
    }
    // lanes 0..3: totals for class q = tid
    float inv = 1.f / L;
    s0 *= inv; s1 *= inv; s2 *= inv; s3 *= inv;
    float nq = s0*s0 + s1*s1 + s2*s2 + s3*s3;
    nq += __shfl_xor(nq, 1); nq += __shfl_xor(nq, 2);   // full ||s||^2 on lanes 0..3
    if (tid < 4){
      if (last){
        if (tid == 0) *out_cls = nq / (1.f + nq);       // ||squash(s)|| = n/(1+n)
      } else {
        float f = sqrtf(nq) / (1.f + nq);               // squash scale
        vbuf[4*tid+0] = s0*f; vbuf[4*tid+1] = s1*f;
        vbuf[4*tid+2] = s2*f; vbuf[4*tid+3] = s3*f;
      }
    }
  }
  __syncthreads();
}

// uj[] must be register-resident: EVERY access compile-time indexed (full
// unroll — R6's partial unroll made uj[s] dynamic -> scratch, +600 MB HBM)
// AND budget 256 VGPR via (512,2) (R5's 128 budget also demoted it).
__global__ void __launch_bounds__(NTH, 2)
caps_route(const float* __restrict__ U, const float* __restrict__ W,
           float* __restrict__ Out){
  __shared__ float red[8][4][5];
  __shared__ float vbuf[16];

  const int tid = threadIdx.x;
  const int qo  = tid & 3;            // my o-quad: o = 4*qo .. 4*qo+3
  const int rg  = tid >> 2;           // route group 0..127
  const int k   = blockIdx.x & 1;
  const int b   = blockIdx.x >> 1;

  const float* Ub = U + (size_t)b * (RT * 4);
  const float* Wk = W + (size_t)k * ((size_t)RT * 64) + qo * 4;

  float4 uj[NSL];                     // fp32 u_ji quads, register-resident
  float4 acc = make_float4(0.f,0.f,0.f,0.f);

  // ---------------- Phase A: build u_ji; fused pass 1 (uniform weights) ----
  // W loads: lane stride 16 B inside 64-B lines, 16 fully-consumed lines per
  // instruction -> fully coalesced.
  #pragma unroll
  for (int s = 0; s < NSL; ++s){
    if (s < NSL-1 || tid < 128){      // wave-uniform guard (slice 18: waves 0-1)
      int route = s*128 + rg;
      float4 u4 = *(const float4*)(Ub + (size_t)route * 4);
      const float* wr = Wk + (size_t)route * 64;
      float4 w0 = *(const float4*)(wr);
      float4 w1 = *(const float4*)(wr + 16);
      float4 w2 = *(const float4*)(wr + 32);
      float4 w3 = *(const float4*)(wr + 48);
      float4 p;
      p.x = u4.x * w0.x; p.y = u4.x * w0.y; p.z = u4.x * w0.z; p.w = u4.x * w0.w;
      p.x = fmaf(u4.y, w1.x, p.x); p.y = fmaf(u4.y, w1.y, p.y);
      p.z = fmaf(u4.y, w1.z, p.z); p.w = fmaf(u4.y, w1.w, p.w);
      p.x = fmaf(u4.z, w2.x, p.x); p.y = fmaf(u4.z, w2.y, p.y);
      p.z = fmaf(u4.z, w2.z, p.z); p.w = fmaf(u4.z, w2.w, p.w);
      p.x = fmaf(u4.w, w3.x, p.x); p.y = fmaf(u4.w, w3.y, p.y);
      p.z = fmaf(u4.w, w3.z, p.z); p.w = fmaf(u4.w, w3.w, p.w);
      uj[s] = p;
      acc.x += p.x; acc.y += p.y; acc.z += p.z; acc.w += p.w;
    } else {
      uj[s] = make_float4(0.f,0.f,0.f,0.f);
    }
  }
  float lcnt = (tid < 128) ? (float)NSL : (float)(NSL-1);  // routes this lane built
  merge_quad(acc, lcnt, tid, red, vbuf, false, nullptr);   // v0 = squash(s0)
  float4 v0 = make_float4(vbuf[4*qo], vbuf[4*qo+1], vbuf[4*qo+2], vbuf[4*qo+3]);

  // ---------------- Pass 2: d = uji.v0 ; c = softmax(d); s1 ---------------
  acc = make_float4(0.f,0.f,0.f,0.f); float l = 0.f;
  #pragma unroll
  for (int s = 0; s < NSL; ++s){
    float4 p = uj[s];
    float d = fmaf(p.x, v0.x, fmaf(p.y, v0.y, fmaf(p.z, v0.z, p.w * v0.w)));
    d += __shfl_xor(d, 1); d += __shfl_xor(d, 2);          // full route dot
    if (s < NSL-1 || tid < 128){
      float e = __expf(d - SH1);
      l += e;
      acc.x = fmaf(e, p.x, acc.x); acc.y = fmaf(e, p.y, acc.y);
      acc.z = fmaf(e, p.z, acc.z); acc.w = fmaf(e, p.w, acc.w);
    }
  }
  merge_quad(acc, l, tid, red, vbuf, false, nullptr);      // v1 = squash(s1)
  // b2 = uji.v0 + uji.v1 = uji.(v0+v1): pass 3 dots with vsum, no d1 storage
  float4 vs = make_float4(v0.x + vbuf[4*qo],   v0.y + vbuf[4*qo+1],
                          v0.z + vbuf[4*qo+2], v0.w + vbuf[4*qo+3]);

  // ---------------- Pass 3: b2 = uji.(v0+v1) ; c = softmax; s2 ------------
  acc = make_float4(0.f,0.f,0.f,0.f); l = 0.f;
  #pragma unroll
  for (int s = 0; s < NSL; ++s){
    float4 p = uj[s];
    float d = fmaf(p.x, vs.x, fmaf(p.y, vs.y, fmaf(p.z, vs.z, p.w * vs.w)));
    d += __shfl_xor(d, 1); d += __shfl_xor(d, 2);
    if (s < NSL-1 || tid < 128){
      float e = __expf(d - SH2);
      l += e;
      acc.x = fmaf(e, p.x, acc.x); acc.y = fmaf(e, p.y, acc.y);
      acc.z = fmaf(e, p.z, acc.z); acc.w = fmaf(e, p.w, acc.w);
    }
  }
  merge_quad(acc, l, tid, red, vbuf, true, Out + blockIdx.x); // logit -> Out[b*2+k]
}

// In-place 2-way softmax over k: Out[b,0..1] fp32
__global__ void caps_softmax(float* __restrict__ Out){
  int b = blockIdx.x * blockDim.x + threadIdx.x;
  if (b < BATCH){
    float2* p = (float2*)Out;
    float2 c = p[b];
    float m  = fmaxf(c.x, c.y);
    float e0 = __expf(c.x - m), e1 = __expf(c.y - m);
    float inv = 1.f / (e0 + e1);
    p[b] = make_float2(e0 * inv, e1 * inv);
  }
}

extern "C" void kernel_launch(void* const* d_in, const int* in_sizes, int n_in,
                              void* d_out, int out_size, void* d_ws, size_t ws_size,
                              hipStream_t stream) {
  const float* U = (const float*)d_in[0];   // [1024, 2336, 4] fp32
  const float* W = (const float*)d_in[1];   // [2, 2336, 4, 16] fp32
  float* Out = (float*)d_out;               // [1024, 2] fp32
  caps_route<<<dim3(NBLK), dim3(NTH), 0, stream>>>(U, W, Out);
  caps_softmax<<<dim3(BATCH / 256), dim3(256), 0, stream>>>(Out);
}